// Round 1
// baseline (527.233 us; speedup 1.0000x reference)
//
#include <hip/hip_runtime.h>

typedef _Float16 f16;
typedef f16   f16x4 __attribute__((ext_vector_type(4)));
typedef f16   f16x8 __attribute__((ext_vector_type(8)));
typedef float f32x2 __attribute__((ext_vector_type(2)));
typedef float f32x4 __attribute__((ext_vector_type(4)));

#define LOG2E 1.44269504088896f

__device__ __forceinline__ float fast_exp(float x) {  // e^x
    return __builtin_amdgcn_exp2f(x * LOG2E);
}
__device__ __forceinline__ float silu_f(float x) {
    return x / (1.f + __builtin_amdgcn_exp2f(-LOG2E * x));
}
__device__ __forceinline__ float softplus_f(float x) {
    if (x > 16.f) return x;
    float e = __builtin_amdgcn_exp2f(x * LOG2E);
    return __builtin_amdgcn_logf(1.f + e) * 0.69314718056f;
}

// DPP-based 16-lane sum reduction (stays on VALU pipe, no ds_swizzle)
#define DPP_ADD(x, ctrl) \
    ((x) + __int_as_float(__builtin_amdgcn_update_dpp(0, __float_as_int(x), (ctrl), 0xF, 0xF, true)))

// ---------------- converts ----------------
__global__ void cvt_f32_f16(const float* __restrict__ in, f16* __restrict__ out, int n4) {
    int i = blockIdx.x * 256 + threadIdx.x;
    if (i < n4) {
        f32x4 v = ((const f32x4*)in)[i];
        f16x4 o = {(f16)v[0], (f16)v[1], (f16)v[2], (f16)v[3]};
        ((f16x4*)out)[i] = o;
    }
}

// W_x (96,2048) f32 -> padded (128,2048) f16, rows 96..127 zero
__global__ void cvt_wx(const float* __restrict__ in, f16* __restrict__ out) {
    int i = blockIdx.x * 256 + threadIdx.x;   // 128*2048 total
    int r = i >> 11;
    out[i] = (r < 96) ? (f16)in[i] : (f16)0.f;
}

// proj (4096,128) f32 cols 0..63 -> dtlo16 (4096,64) f16
__global__ void cvt_dtlo(const float* __restrict__ proj, f16* __restrict__ out) {
    int i = blockIdx.x * 256 + threadIdx.x;   // per 4 elems, 65536 total
    int m = i >> 4, c0 = (i & 15) * 4;
    f32x4 v = *(const f32x4*)(proj + (size_t)m * 128 + c0);
    f16x4 o = {(f16)v[0], (f16)v[1], (f16)v[2], (f16)v[3]};
    *(f16x4*)(out + (size_t)m * 64 + c0) = o;
}

// ---------------- GEMM: C[m,n] = sum_k A[m,k] * B[n,k]  (both K-major fp16, fp32 acc)
// EPI: 0 = plain store, 1 = softplus(acc + bias[n])
template <int EPI, typename OutT>
__global__ __launch_bounds__(256) void gemm_tn(const f16* __restrict__ A, const f16* __restrict__ B,
                                               OutT* __restrict__ C, const float* __restrict__ bias,
                                               int M, int N, int K) {
    __shared__ f16 As[128][40];   // 40-half rows: 80B stride -> conflict-free-ish ds_read_b128
    __shared__ f16 Bs[128][40];
    const int tid = threadIdx.x;
    const int w = tid >> 6, l = tid & 63;
    const int wm = (w >> 1) * 64, wn = (w & 1) * 64;
    const int lrow = l & 15, lk8 = (l >> 4) * 8;
    const int mt = blockIdx.y, nt = blockIdx.x;

    f32x4 acc[4][4];
#pragma unroll
    for (int i = 0; i < 4; i++)
#pragma unroll
        for (int j = 0; j < 4; j++) acc[i][j] = (f32x4){0.f, 0.f, 0.f, 0.f};

    const int r0 = tid >> 2, kc0 = (tid & 3) * 8;
    const int r1 = r0 + 64;
    const f16* Ab = A + (size_t)(mt * 128) * K;
    const f16* Bb = B + (size_t)(nt * 128) * K;

    for (int kt = 0; kt < K; kt += 32) {
        uint4 a0 = *(const uint4*)(Ab + (size_t)r0 * K + kt + kc0);
        uint4 a1 = *(const uint4*)(Ab + (size_t)r1 * K + kt + kc0);
        uint4 b0 = *(const uint4*)(Bb + (size_t)r0 * K + kt + kc0);
        uint4 b1 = *(const uint4*)(Bb + (size_t)r1 * K + kt + kc0);
        *(uint4*)&As[r0][kc0] = a0;
        *(uint4*)&As[r1][kc0] = a1;
        *(uint4*)&Bs[r0][kc0] = b0;
        *(uint4*)&Bs[r1][kc0] = b1;
        __syncthreads();
        f16x8 af[4], bf[4];
#pragma unroll
        for (int i = 0; i < 4; i++) {
            af[i] = *(const f16x8*)&As[wm + i * 16 + lrow][lk8];
            bf[i] = *(const f16x8*)&Bs[wn + i * 16 + lrow][lk8];
        }
#pragma unroll
        for (int i = 0; i < 4; i++)
#pragma unroll
            for (int j = 0; j < 4; j++)
                acc[i][j] = __builtin_amdgcn_mfma_f32_16x16x32_f16(af[i], bf[j], acc[i][j], 0, 0, 0);
        __syncthreads();
    }

    // C/D layout: col = lane&15, row = (lane>>4)*4 + reg   [guide §3, m89-verified]
    const int orow = mt * 128 + wm + (l >> 4) * 4;
    const int ocol = nt * 128 + wn + (l & 15);
#pragma unroll
    for (int fm = 0; fm < 4; fm++)
#pragma unroll
        for (int fn = 0; fn < 4; fn++) {
            int c = ocol + fn * 16;
            float bv = (EPI == 1) ? bias[c] : 0.f;
#pragma unroll
            for (int i = 0; i < 4; i++) {
                float v = acc[fm][fn][i];
                if (EPI == 1) v = softplus_f(v + bv);
                C[(size_t)(orow + fm * 16 + i) * N + c] = (OutT)v;
            }
        }
}

// ---------------- depthwise causal conv1d + SiLU ----------------
// xz: (4096, 4096) f16, x = cols [0,2048). out xc: (4096, 2048) f16
__global__ __launch_bounds__(256) void conv_silu_k(const f16* __restrict__ xz, const float* __restrict__ cw,
                                                   const float* __restrict__ cb, f16* __restrict__ xc) {
    int idx = blockIdx.x * 256 + threadIdx.x;  // one thread per 8 channels
    int m = idx >> 8;
    int d0 = (idx & 255) * 8;
    int l = m & 2047;
    float r[8];
    f32x4 cwv[8];
#pragma unroll
    for (int j = 0; j < 8; j++) {
        r[j] = cb[d0 + j];
        cwv[j] = *(const f32x4*)(cw + (size_t)(d0 + j) * 4);
    }
#pragma unroll
    for (int k = 0; k < 4; k++) {
        int ls = l - 3 + k;
        if (ls >= 0) {
            f16x8 xv = *(const f16x8*)(xz + (size_t)(m + k - 3) * 4096 + d0);
#pragma unroll
            for (int j = 0; j < 8; j++) r[j] += cwv[j][k] * (float)xv[j];
        }
    }
    f16x8 o;
#pragma unroll
    for (int j = 0; j < 8; j++) o[j] = (f16)silu_f(r[j]);
    *(f16x8*)(xc + (size_t)m * 2048 + d0) = o;
}

// ---------------- selective scan (+ fused D*x and SiLU(z) gating) ----------------
// 16 lanes per (b,d): lane n owns state n. 256 threads = 16 (b,d) chains per block.
__global__ __launch_bounds__(256) void scan_k(const float* __restrict__ dt, const f16* __restrict__ xc,
                                              const f16* __restrict__ xz, const float* __restrict__ proj,
                                              const float* __restrict__ A_log, const float* __restrict__ Dp,
                                              f16* __restrict__ y16) {
    __shared__ f32x4 dtxz_s[2][64][16];  // {dt, x, z, -} per (t,d) : 32KB
    __shared__ f32x2 bc_s[2][64][16];    // {B,C} per (t,n)         : 16KB
    const int tid = threadIdx.x;
    const int b = blockIdx.x >> 7;
    const int d_base = (blockIdx.x & 127) << 4;
    const int g = tid >> 4, n = tid & 15;
    const int d = d_base + g;
    const float a = -fast_exp(A_log[d * 16 + n]);   // A = -exp(A_log)
    const float al2 = a * LOG2E;
    const float Dv = Dp[d];
    const size_t mb = (size_t)b * 2048;
    float h = 0.f;

    // stage chunk 0
#pragma unroll
    for (int i = 0; i < 4; i++) {
        int idx = i * 256 + tid, tt = idx >> 4, j = idx & 15;
        size_t row = mb + tt;
        float dtv = dt[row * 2048 + d_base + j];
        float xv = (float)xc[row * 2048 + d_base + j];
        float zv = (float)xz[row * 4096 + 2048 + d_base + j];
        dtxz_s[0][tt][j] = (f32x4){dtv, xv, zv, 0.f};
        bc_s[0][tt][j] = (f32x2){proj[row * 128 + 64 + j], proj[row * 128 + 80 + j]};
    }
    __syncthreads();

    float rdt[4], rx[4], rz[4], rB[4], rC[4];
    for (int c = 0; c < 32; c++) {
        const int buf = c & 1;
        const int t0 = c * 64;
        if (c < 31) {  // prefetch next chunk into registers (overlaps with compute)
#pragma unroll
            for (int i = 0; i < 4; i++) {
                int idx = i * 256 + tid, tt = idx >> 4, j = idx & 15;
                size_t row = mb + t0 + 64 + tt;
                rdt[i] = dt[row * 2048 + d_base + j];
                rx[i] = (float)xc[row * 2048 + d_base + j];
                rz[i] = (float)xz[row * 4096 + 2048 + d_base + j];
                rB[i] = proj[row * 128 + 64 + j];
                rC[i] = proj[row * 128 + 80 + j];
            }
        }
#pragma unroll 8
        for (int tt = 0; tt < 64; tt++) {
            f32x4 dxz = dtxz_s[buf][tt][g];   // broadcast within 16-lane group
            f32x2 bc = bc_s[buf][tt][n];
            float dA = __builtin_amdgcn_exp2f(dxz[0] * al2);  // exp(dt*A)
            float u = dxz[0] * dxz[1];                        // dt*x
            h = fmaf(dA, h, u * bc[0]);
            float yp = h * bc[1];
            // 16-lane sum via DPP (VALU pipe): xor1, xor2, half-mirror(8), mirror(16)
            yp = DPP_ADD(yp, 0xB1);
            yp = DPP_ADD(yp, 0x4E);
            yp = DPP_ADD(yp, 0x141);
            yp = DPP_ADD(yp, 0x140);
            float yv = (yp + Dv * dxz[1]) * silu_f(dxz[2]);
            if (n == 0) y16[(mb + t0 + tt) * 2048 + d] = (f16)yv;
        }
        if (c < 31) {
#pragma unroll
            for (int i = 0; i < 4; i++) {
                int idx = i * 256 + tid, tt = idx >> 4, j = idx & 15;
                dtxz_s[buf ^ 1][tt][j] = (f32x4){rdt[i], rx[i], rz[i], 0.f};
                bc_s[buf ^ 1][tt][j] = (f32x2){rB[i], rC[i]};
            }
            __syncthreads();
        }
    }
}

extern "C" void kernel_launch(void* const* d_in, const int* in_sizes, int n_in,
                              void* d_out, int out_size, void* d_ws, size_t ws_size,
                              hipStream_t stream) {
    const float* hidden = (const float*)d_in[0];
    const float* W_in   = (const float*)d_in[1];
    const float* conv_w = (const float*)d_in[2];
    const float* conv_b = (const float*)d_in[3];
    const float* W_x    = (const float*)d_in[4];
    const float* W_dt   = (const float*)d_in[5];
    const float* b_dt   = (const float*)d_in[6];
    const float* A_log  = (const float*)d_in[7];
    const float* D_par  = (const float*)d_in[8];
    const float* W_out  = (const float*)d_in[9];
    float* out = (float*)d_out;

    char* ws = (char*)d_ws;
    size_t off = 0;
    auto alloc = [&](size_t bytes) { void* p = ws + off; off += (bytes + 255) & ~(size_t)255; return p; };
    f16* h16     = (f16*)alloc(4096ull * 1024 * 2);
    f16* Win16   = (f16*)alloc(4096ull * 1024 * 2);
    f16* Wx16    = (f16*)alloc(128ull * 2048 * 2);
    f16* Wdt16   = (f16*)alloc(2048ull * 64 * 2);
    f16* Wout16  = (f16*)alloc(1024ull * 2048 * 2);
    f16* xz16    = (f16*)alloc(4096ull * 4096 * 2);
    f16* xc16    = (f16*)alloc(4096ull * 2048 * 2);
    float* proj  = (float*)alloc(4096ull * 128 * 4);
    f16* dtlo16  = (f16*)alloc(4096ull * 64 * 2);
    float* dt32  = (float*)alloc(4096ull * 2048 * 4);
    f16* y16     = (f16*)alloc(4096ull * 2048 * 2);
    (void)ws_size; (void)in_sizes; (void)n_in; (void)out_size;

    // fp32 -> fp16 operand prep
    cvt_f32_f16<<<4096, 256, 0, stream>>>(hidden, h16, 1048576);
    cvt_f32_f16<<<4096, 256, 0, stream>>>(W_in, Win16, 1048576);
    cvt_wx<<<1024, 256, 0, stream>>>(W_x, Wx16);
    cvt_f32_f16<<<128, 256, 0, stream>>>(W_dt, Wdt16, 32768);
    cvt_f32_f16<<<2048, 256, 0, stream>>>(W_out, Wout16, 524288);

    // in_proj: xz = hidden @ W_in^T   (4096 x 4096 x 1024)
    gemm_tn<0, f16><<<dim3(32, 32), 256, 0, stream>>>(h16, Win16, xz16, nullptr, 4096, 4096, 1024);
    // depthwise conv + SiLU
    conv_silu_k<<<4096, 256, 0, stream>>>(xz16, conv_w, conv_b, xc16);
    // x_proj: proj = xc @ Wx^T (N padded to 128)
    gemm_tn<0, float><<<dim3(1, 32), 256, 0, stream>>>(xc16, Wx16, proj, nullptr, 4096, 128, 2048);
    // dt = softplus(dtlo @ W_dt^T + b_dt)
    cvt_dtlo<<<256, 256, 0, stream>>>(proj, dtlo16);
    gemm_tn<1, float><<<dim3(16, 32), 256, 0, stream>>>(dtlo16, Wdt16, dt32, b_dt, 4096, 2048, 64);
    // selective scan + gating -> y16
    scan_k<<<256, 256, 0, stream>>>(dt32, xc16, xz16, proj, A_log, D_par, y16);
    // out_proj: out = y @ W_out^T
    gemm_tn<0, float><<<dim3(8, 32), 256, 0, stream>>>(y16, Wout16, out, nullptr, 4096, 1024, 2048);
}

// Round 2
// 317.082 us; speedup vs baseline: 1.6628x; 1.6628x over previous
//
#include <hip/hip_runtime.h>

typedef _Float16 f16;
typedef f16   f16x2 __attribute__((ext_vector_type(2)));
typedef f16   f16x4 __attribute__((ext_vector_type(4)));
typedef f16   f16x8 __attribute__((ext_vector_type(8)));
typedef float f32x2 __attribute__((ext_vector_type(2)));
typedef float f32x4 __attribute__((ext_vector_type(4)));

#define LOG2E 1.44269504088896f

__device__ __forceinline__ float fast_exp(float x) {  // e^x
    return __builtin_amdgcn_exp2f(x * LOG2E);
}
__device__ __forceinline__ float silu_f(float x) {
    return x / (1.f + __builtin_amdgcn_exp2f(-LOG2E * x));
}
__device__ __forceinline__ float softplus_f(float x) {
    if (x > 16.f) return x;
    float e = __builtin_amdgcn_exp2f(x * LOG2E);
    return __builtin_amdgcn_logf(1.f + e) * 0.69314718056f;
}

// DPP-based 16-lane sum reduction (stays on VALU pipe, no ds_swizzle)
#define DPP_ADD(x, ctrl) \
    ((x) + __int_as_float(__builtin_amdgcn_update_dpp(0, __float_as_int(x), (ctrl), 0xF, 0xF, true)))

// ---------------- converts ----------------
__global__ void cvt_f32_f16(const float* __restrict__ in, f16* __restrict__ out, int n4) {
    int i = blockIdx.x * 256 + threadIdx.x;
    if (i < n4) {
        f32x4 v = ((const f32x4*)in)[i];
        f16x4 o = {(f16)v[0], (f16)v[1], (f16)v[2], (f16)v[3]};
        ((f16x4*)out)[i] = o;
    }
}

// W_x (96,2048) f32 -> padded (128,2048) f16, rows 96..127 zero
__global__ void cvt_wx(const float* __restrict__ in, f16* __restrict__ out) {
    int i = blockIdx.x * 256 + threadIdx.x;   // 128*2048 total
    int r = i >> 11;
    out[i] = (r < 96) ? (f16)in[i] : (f16)0.f;
}

// proj (4096,128) f32 cols 0..63 -> dtlo16 (4096,64) f16
__global__ void cvt_dtlo(const float* __restrict__ proj, f16* __restrict__ out) {
    int i = blockIdx.x * 256 + threadIdx.x;   // per 4 elems, 65536 total
    int m = i >> 4, c0 = (i & 15) * 4;
    f32x4 v = *(const f32x4*)(proj + (size_t)m * 128 + c0);
    f16x4 o = {(f16)v[0], (f16)v[1], (f16)v[2], (f16)v[3]};
    *(f16x4*)(out + (size_t)m * 64 + c0) = o;
}

// ---------------- GEMM: C[m,n] = sum_k A[m,k] * B[n,k]  (both K-major fp16, fp32 acc)
// EPI: 0 = plain store, 1 = softplus(acc + bias[n])
template <int EPI, typename OutT>
__global__ __launch_bounds__(256) void gemm_tn(const f16* __restrict__ A, const f16* __restrict__ B,
                                               OutT* __restrict__ C, const float* __restrict__ bias,
                                               int M, int N, int K) {
    __shared__ f16 As[128][40];   // 40-half rows: 80B stride -> conflict-free-ish ds_read_b128
    __shared__ f16 Bs[128][40];
    const int tid = threadIdx.x;
    const int w = tid >> 6, l = tid & 63;
    const int wm = (w >> 1) * 64, wn = (w & 1) * 64;
    const int lrow = l & 15, lk8 = (l >> 4) * 8;
    const int mt = blockIdx.y, nt = blockIdx.x;

    f32x4 acc[4][4];
#pragma unroll
    for (int i = 0; i < 4; i++)
#pragma unroll
        for (int j = 0; j < 4; j++) acc[i][j] = (f32x4){0.f, 0.f, 0.f, 0.f};

    const int r0 = tid >> 2, kc0 = (tid & 3) * 8;
    const int r1 = r0 + 64;
    const f16* Ab = A + (size_t)(mt * 128) * K;
    const f16* Bb = B + (size_t)(nt * 128) * K;

    for (int kt = 0; kt < K; kt += 32) {
        uint4 a0 = *(const uint4*)(Ab + (size_t)r0 * K + kt + kc0);
        uint4 a1 = *(const uint4*)(Ab + (size_t)r1 * K + kt + kc0);
        uint4 b0 = *(const uint4*)(Bb + (size_t)r0 * K + kt + kc0);
        uint4 b1 = *(const uint4*)(Bb + (size_t)r1 * K + kt + kc0);
        *(uint4*)&As[r0][kc0] = a0;
        *(uint4*)&As[r1][kc0] = a1;
        *(uint4*)&Bs[r0][kc0] = b0;
        *(uint4*)&Bs[r1][kc0] = b1;
        __syncthreads();
        f16x8 af[4], bf[4];
#pragma unroll
        for (int i = 0; i < 4; i++) {
            af[i] = *(const f16x8*)&As[wm + i * 16 + lrow][lk8];
            bf[i] = *(const f16x8*)&Bs[wn + i * 16 + lrow][lk8];
        }
#pragma unroll
        for (int i = 0; i < 4; i++)
#pragma unroll
            for (int j = 0; j < 4; j++)
                acc[i][j] = __builtin_amdgcn_mfma_f32_16x16x32_f16(af[i], bf[j], acc[i][j], 0, 0, 0);
        __syncthreads();
    }

    // C/D layout: col = lane&15, row = (lane>>4)*4 + reg   [guide §3, m89-verified]
    const int orow = mt * 128 + wm + (l >> 4) * 4;
    const int ocol = nt * 128 + wn + (l & 15);
#pragma unroll
    for (int fm = 0; fm < 4; fm++)
#pragma unroll
        for (int fn = 0; fn < 4; fn++) {
            int c = ocol + fn * 16;
            float bv = (EPI == 1) ? bias[c] : 0.f;
#pragma unroll
            for (int i = 0; i < 4; i++) {
                float v = acc[fm][fn][i];
                if (EPI == 1) v = softplus_f(v + bv);
                C[(size_t)(orow + fm * 16 + i) * N + c] = (OutT)v;
            }
        }
}

// ---------------- depthwise causal conv1d + SiLU ----------------
__global__ __launch_bounds__(256) void conv_silu_k(const f16* __restrict__ xz, const float* __restrict__ cw,
                                                   const float* __restrict__ cb, f16* __restrict__ xc) {
    int idx = blockIdx.x * 256 + threadIdx.x;  // one thread per 8 channels
    int m = idx >> 8;
    int d0 = (idx & 255) * 8;
    int l = m & 2047;
    float r[8];
    f32x4 cwv[8];
#pragma unroll
    for (int j = 0; j < 8; j++) {
        r[j] = cb[d0 + j];
        cwv[j] = *(const f32x4*)(cw + (size_t)(d0 + j) * 4);
    }
#pragma unroll
    for (int k = 0; k < 4; k++) {
        int ls = l - 3 + k;
        if (ls >= 0) {
            f16x8 xv = *(const f16x8*)(xz + (size_t)(m + k - 3) * 4096 + d0);
#pragma unroll
            for (int j = 0; j < 8; j++) r[j] += cwv[j][k] * (float)xv[j];
        }
    }
    f16x8 o;
#pragma unroll
    for (int j = 0; j < 8; j++) o[j] = (f16)silu_f(r[j]);
    *(f16x8*)(xc + (size_t)m * 2048 + d0) = o;
}

// ---------------- chunked selective scan ----------------
// L=2048 split into NCHUNK=16 chunks of CT=128. 16 lanes per (b,d) chain (lane n = state n),
// 16 chains per block. grid = (chunk, dgroup=128, b=2).
#define CT 128
#define NCHUNK 16
#define NSTATE 65536   // 2 * 2048 * 16

// Pass 1: local scan from h=0 -> Hend; chunk decay P = exp(A * sum_t dt)
__global__ __launch_bounds__(256) void scan_p1(const float* __restrict__ dt, const f16* __restrict__ xc,
                                               const float* __restrict__ proj, const float* __restrict__ A_log,
                                               float* __restrict__ Pbuf, float* __restrict__ Hend) {
    __shared__ f32x2 dtx_s[CT][16];  // {dt, x}   16KB
    __shared__ float b_s[CT][16];    // B          8KB
    const int tid = threadIdx.x;
    const int c = blockIdx.x, dg = blockIdx.y, b = blockIdx.z;
    const int d_base = dg << 4;
    const int g = tid >> 4, n = tid & 15;
    const int d = d_base + g;
    const float al2 = -fast_exp(A_log[d * 16 + n]) * LOG2E;
    const size_t mb = (size_t)b * 2048 + c * CT;

#pragma unroll
    for (int i = 0; i < 8; i++) {
        int idx = i * 256 + tid, tt = idx >> 4, j = idx & 15;
        size_t row = mb + tt;
        dtx_s[tt][j] = (f32x2){dt[row * 2048 + d_base + j], (float)xc[row * 2048 + d_base + j]};
        b_s[tt][j] = proj[row * 128 + 64 + j];
    }
    __syncthreads();

    float h = 0.f, sdt = 0.f;
#pragma unroll 8
    for (int t = 0; t < CT; t++) {
        f32x2 dx = dtx_s[t][g];
        float Bv = b_s[t][n];
        float dA = __builtin_amdgcn_exp2f(dx[0] * al2);
        sdt += dx[0];
        h = fmaf(dA, h, dx[0] * dx[1] * Bv);
    }
    const int sidx = ((b << 11) + d_base) * 16 + tid;  // ((b*2048+d)*16+n), contiguous in tid
    Pbuf[c * NSTATE + sidx] = __builtin_amdgcn_exp2f(al2 * sdt);
    Hend[c * NSTATE + sidx] = h;
}

// Combine: sequential prefix over the 16 chunks (parallel over 65536 states)
__global__ __launch_bounds__(256) void scan_combine(const float* __restrict__ Pbuf, const float* __restrict__ Hend,
                                                    float* __restrict__ Hinit) {
    int s = blockIdx.x * 256 + threadIdx.x;
    float h = 0.f;
#pragma unroll
    for (int c = 0; c < NCHUNK; c++) {
        Hinit[c * NSTATE + s] = h;
        h = fmaf(Pbuf[c * NSTATE + s], h, Hend[c * NSTATE + s]);
    }
}

// Pass 2: full scan per chunk seeded with Hinit; fused y = (C.h + D*x)*silu(z)
__global__ __launch_bounds__(256) void scan_p2(const float* __restrict__ dt, const f16* __restrict__ xc,
                                               const f16* __restrict__ xz, const float* __restrict__ proj,
                                               const float* __restrict__ A_log, const float* __restrict__ Dp,
                                               const float* __restrict__ Hinit, f16* __restrict__ y16) {
    __shared__ f32x2 dtx_s[CT][16];  // {dt, pack(x f16, silu(z) f16)}  16KB
    __shared__ f32x2 bc_s[CT][16];   // {B, C}                          16KB
    const int tid = threadIdx.x;
    const int c = blockIdx.x, dg = blockIdx.y, b = blockIdx.z;
    const int d_base = dg << 4;
    const int g = tid >> 4, n = tid & 15;
    const int d = d_base + g;
    const float al2 = -fast_exp(A_log[d * 16 + n]) * LOG2E;
    const float Dv = Dp[d];
    const size_t mb = (size_t)b * 2048 + c * CT;

#pragma unroll
    for (int i = 0; i < 8; i++) {
        int idx = i * 256 + tid, tt = idx >> 4, j = idx & 15;
        size_t row = mb + tt;
        f16 xh = xc[row * 2048 + d_base + j];
        float zv = (float)xz[row * 4096 + 2048 + d_base + j];
        union { f16x2 h2; float f; } u2;
        u2.h2[0] = xh;
        u2.h2[1] = (f16)silu_f(zv);
        dtx_s[tt][j] = (f32x2){dt[row * 2048 + d_base + j], u2.f};
        bc_s[tt][j] = (f32x2){proj[row * 128 + 64 + j], proj[row * 128 + 80 + j]};
    }
    const int sidx = ((b << 11) + d_base) * 16 + tid;
    float h = Hinit[c * NSTATE + sidx];
    __syncthreads();

#pragma unroll 8
    for (int t = 0; t < CT; t++) {
        f32x2 dtx = dtx_s[t][g];
        f32x2 bc = bc_s[t][n];
        union { float f; f16x2 h2; } u2;
        u2.f = dtx[1];
        float xv = (float)u2.h2[0], sz = (float)u2.h2[1];
        float dA = __builtin_amdgcn_exp2f(dtx[0] * al2);
        h = fmaf(dA, h, dtx[0] * xv * bc[0]);
        float yp = h * bc[1];
        yp = DPP_ADD(yp, 0xB1);   // xor 1 (quad_perm)
        yp = DPP_ADD(yp, 0x4E);   // xor 2 (quad_perm)
        yp = DPP_ADD(yp, 0x141);  // xor 4 (row_half_mirror)
        yp = DPP_ADD(yp, 0x140);  // xor 8 (row_mirror)
        float yv = fmaf(Dv, xv, yp) * sz;
        if (n == 0) y16[(mb + t) * 2048 + d] = (f16)yv;
    }
}

extern "C" void kernel_launch(void* const* d_in, const int* in_sizes, int n_in,
                              void* d_out, int out_size, void* d_ws, size_t ws_size,
                              hipStream_t stream) {
    const float* hidden = (const float*)d_in[0];
    const float* W_in   = (const float*)d_in[1];
    const float* conv_w = (const float*)d_in[2];
    const float* conv_b = (const float*)d_in[3];
    const float* W_x    = (const float*)d_in[4];
    const float* W_dt   = (const float*)d_in[5];
    const float* b_dt   = (const float*)d_in[6];
    const float* A_log  = (const float*)d_in[7];
    const float* D_par  = (const float*)d_in[8];
    const float* W_out  = (const float*)d_in[9];
    float* out = (float*)d_out;

    char* ws = (char*)d_ws;
    size_t off = 0;
    auto alloc = [&](size_t bytes) { void* p = ws + off; off += (bytes + 255) & ~(size_t)255; return p; };
    f16* h16     = (f16*)alloc(4096ull * 1024 * 2);
    f16* Win16   = (f16*)alloc(4096ull * 1024 * 2);
    f16* Wx16    = (f16*)alloc(128ull * 2048 * 2);
    f16* Wdt16   = (f16*)alloc(2048ull * 64 * 2);
    f16* Wout16  = (f16*)alloc(1024ull * 2048 * 2);
    f16* xz16    = (f16*)alloc(4096ull * 4096 * 2);
    f16* xc16    = (f16*)alloc(4096ull * 2048 * 2);
    float* proj  = (float*)alloc(4096ull * 128 * 4);
    f16* dtlo16  = (f16*)alloc(4096ull * 64 * 2);
    float* dt32  = (float*)alloc(4096ull * 2048 * 4);
    f16* y16     = (f16*)alloc(4096ull * 2048 * 2);
    float* Pbuf  = (float*)alloc((size_t)NCHUNK * NSTATE * 4);
    float* Hend  = (float*)alloc((size_t)NCHUNK * NSTATE * 4);
    float* Hinit = (float*)alloc((size_t)NCHUNK * NSTATE * 4);
    (void)ws_size; (void)in_sizes; (void)n_in; (void)out_size;

    // fp32 -> fp16 operand prep
    cvt_f32_f16<<<4096, 256, 0, stream>>>(hidden, h16, 1048576);
    cvt_f32_f16<<<4096, 256, 0, stream>>>(W_in, Win16, 1048576);
    cvt_wx<<<1024, 256, 0, stream>>>(W_x, Wx16);
    cvt_f32_f16<<<128, 256, 0, stream>>>(W_dt, Wdt16, 32768);
    cvt_f32_f16<<<2048, 256, 0, stream>>>(W_out, Wout16, 524288);

    // in_proj: xz = hidden @ W_in^T   (4096 x 4096 x 1024)
    gemm_tn<0, f16><<<dim3(32, 32), 256, 0, stream>>>(h16, Win16, xz16, nullptr, 4096, 4096, 1024);
    // depthwise conv + SiLU
    conv_silu_k<<<4096, 256, 0, stream>>>(xz16, conv_w, conv_b, xc16);
    // x_proj: proj = xc @ Wx^T (N padded to 128)
    gemm_tn<0, float><<<dim3(1, 32), 256, 0, stream>>>(xc16, Wx16, proj, nullptr, 4096, 128, 2048);
    // dt = softplus(dtlo @ W_dt^T + b_dt)
    cvt_dtlo<<<256, 256, 0, stream>>>(proj, dtlo16);
    gemm_tn<1, float><<<dim3(16, 32), 256, 0, stream>>>(dtlo16, Wdt16, dt32, b_dt, 4096, 2048, 64);
    // chunked selective scan + gating -> y16
    scan_p1<<<dim3(NCHUNK, 128, 2), 256, 0, stream>>>(dt32, xc16, proj, A_log, Pbuf, Hend);
    scan_combine<<<256, 256, 0, stream>>>(Pbuf, Hend, Hinit);
    scan_p2<<<dim3(NCHUNK, 128, 2), 256, 0, stream>>>(dt32, xc16, xz16, proj, A_log, D_par, Hinit, y16);
    // out_proj: out = y @ W_out^T
    gemm_tn<0, float><<<dim3(8, 32), 256, 0, stream>>>(y16, Wout16, out, nullptr, 4096, 1024, 2048);
}

// Round 3
// 241.676 us; speedup vs baseline: 2.1816x; 1.3120x over previous
//
#include <hip/hip_runtime.h>

typedef _Float16 f16;
typedef f16   f16x2 __attribute__((ext_vector_type(2)));
typedef f16   f16x4 __attribute__((ext_vector_type(4)));
typedef f16   f16x8 __attribute__((ext_vector_type(8)));
typedef float f32x2 __attribute__((ext_vector_type(2)));
typedef float f32x4 __attribute__((ext_vector_type(4)));

#define LOG2E 1.44269504088896f

__device__ __forceinline__ float fast_exp(float x) {  // e^x
    return __builtin_amdgcn_exp2f(x * LOG2E);
}
__device__ __forceinline__ float silu_f(float x) {
    return x / (1.f + __builtin_amdgcn_exp2f(-LOG2E * x));
}
__device__ __forceinline__ float softplus_f(float x) {
    if (x > 16.f) return x;
    float e = __builtin_amdgcn_exp2f(x * LOG2E);
    return __builtin_amdgcn_logf(1.f + e) * 0.69314718056f;
}

// DPP-based sum (VALU pipe). Validated ctrls: 0xB1 xor1, 0x4E xor2, 0x141 half-mirror.
#define DPP_ADD(x, ctrl) \
    ((x) + __int_as_float(__builtin_amdgcn_update_dpp(0, __float_as_int(x), (ctrl), 0xF, 0xF, true)))

__device__ __forceinline__ void gload_lds16(const void* g, void* l) {
    __builtin_amdgcn_global_load_lds((__attribute__((address_space(1))) void*)(g),
                                     (__attribute__((address_space(3))) void*)(l), 16, 0, 0);
}

// ---------------- converts ----------------
__global__ void cvt_f32_f16(const float* __restrict__ in, f16* __restrict__ out, int n4) {
    int i = blockIdx.x * 256 + threadIdx.x;
    if (i < n4) {
        f32x4 v = ((const f32x4*)in)[i];
        f16x4 o = {(f16)v[0], (f16)v[1], (f16)v[2], (f16)v[3]};
        ((f16x4*)out)[i] = o;
    }
}

// W_x (96,2048) f32 -> padded (128,2048) f16, rows 96..127 zero
__global__ void cvt_wx(const float* __restrict__ in, f16* __restrict__ out) {
    int i = blockIdx.x * 256 + threadIdx.x;
    int r = i >> 11;
    out[i] = (r < 96) ? (f16)in[i] : (f16)0.f;
}

// sum 8 split-K partials -> proj f32 ; also emit dtlo16 (cols 0..63)
__global__ void reduce_proj(const float* __restrict__ Pws, float* __restrict__ proj,
                            f16* __restrict__ dtlo) {
    int i = blockIdx.x * 256 + threadIdx.x;  // 4096*128/4 = 131072
    int m = i >> 5, c0 = (i & 31) * 4;
    f32x4 s = {0.f, 0.f, 0.f, 0.f};
#pragma unroll
    for (int z = 0; z < 8; z++)
        s += *(const f32x4*)(Pws + (size_t)z * 4096 * 128 + (size_t)m * 128 + c0);
    *(f32x4*)(proj + (size_t)m * 128 + c0) = s;
    if (c0 < 64) {
        f16x4 o = {(f16)s[0], (f16)s[1], (f16)s[2], (f16)s[3]};
        *(f16x4*)(dtlo + (size_t)m * 64 + c0) = o;
    }
}

// ---------------- GEMM (m97 structure): C[m,n] = sum_k A[m,k]*B[n,k], global_load_lds staging
// EPI: 0 = plain store, 1 = softplus(acc + bias[n]).  split-K via gridDim.z: kbeg = z*kstep.
template <int EPI, typename OutT>
__global__ __launch_bounds__(256) void gemm_gl(const f16* __restrict__ A, const f16* __restrict__ B,
                                               OutT* __restrict__ C, const float* __restrict__ bias,
                                               int M, int N, int K, int kstep) {
    __shared__ f16 As[128 * 64];  // linear: row-major [128][64], 16KB
    __shared__ f16 Bs[128 * 64];
    const int tid = threadIdx.x;
    const int w = tid >> 6, l = tid & 63;
    const int wm = (w >> 1) * 64, wn = (w & 1) * 64;
    const int lrow = l & 15, lk8 = (l >> 4) * 8;
    const int mt = blockIdx.y, nt = blockIdx.x;
    const int kbeg = blockIdx.z * kstep, kend = kbeg + kstep;
    OutT* Cz = C + (size_t)blockIdx.z * M * N;

    f32x4 acc[4][4];
#pragma unroll
    for (int i = 0; i < 4; i++)
#pragma unroll
        for (int j = 0; j < 4; j++) acc[i][j] = (f32x4){0.f, 0.f, 0.f, 0.f};

    // staging: wave w covers tile rows [w*32, w*32+32), 4 calls x (8 rows = 64 lanes x 16B)
    const int srow = w * 32 + (l >> 3);
    const int scol = (l & 7) * 8;  // halves
    const f16* Ag = A + (size_t)(mt * 128 + srow) * K + scol;
    const f16* Bg = B + (size_t)(nt * 128 + srow) * K + scol;
    f16* AsW = As + (w * 32) * 64;  // wave-uniform LDS base
    f16* BsW = Bs + (w * 32) * 64;

    for (int kt = kbeg; kt < kend; kt += 64) {
#pragma unroll
        for (int i = 0; i < 4; i++) {
            gload_lds16(Ag + kt + (size_t)i * 8 * K, AsW + i * 512);
            gload_lds16(Bg + kt + (size_t)i * 8 * K, BsW + i * 512);
        }
        __syncthreads();  // drains vmcnt + lgkmcnt
#pragma unroll
        for (int kk = 0; kk < 64; kk += 32) {
            f16x8 af[4], bf[4];
#pragma unroll
            for (int i = 0; i < 4; i++) {
                af[i] = *(const f16x8*)&As[(wm + i * 16 + lrow) * 64 + kk + lk8];
                bf[i] = *(const f16x8*)&Bs[(wn + i * 16 + lrow) * 64 + kk + lk8];
            }
#pragma unroll
            for (int i = 0; i < 4; i++)
#pragma unroll
                for (int j = 0; j < 4; j++)
                    acc[i][j] = __builtin_amdgcn_mfma_f32_16x16x32_f16(af[i], bf[j], acc[i][j], 0, 0, 0);
        }
        __syncthreads();
    }

    const int orow = mt * 128 + wm + (l >> 4) * 4;
    const int ocol = nt * 128 + wn + (l & 15);
#pragma unroll
    for (int fm = 0; fm < 4; fm++)
#pragma unroll
        for (int fn = 0; fn < 4; fn++) {
            int c = ocol + fn * 16;
            float bv = (EPI == 1) ? bias[c] : 0.f;
#pragma unroll
            for (int i = 0; i < 4; i++) {
                float v = acc[fm][fn][i];
                if (EPI == 1) v = softplus_f(v + bv);
                Cz[(size_t)(orow + fm * 16 + i) * N + c] = (OutT)v;
            }
        }
}

// ---------------- depthwise causal conv1d + SiLU ----------------
__global__ __launch_bounds__(256) void conv_silu_k(const f16* __restrict__ xz, const float* __restrict__ cw,
                                                   const float* __restrict__ cb, f16* __restrict__ xc) {
    int idx = blockIdx.x * 256 + threadIdx.x;  // one thread per 8 channels
    int m = idx >> 8;
    int d0 = (idx & 255) * 8;
    int l = m & 2047;
    float r[8];
    f32x4 cwv[8];
#pragma unroll
    for (int j = 0; j < 8; j++) {
        r[j] = cb[d0 + j];
        cwv[j] = *(const f32x4*)(cw + (size_t)(d0 + j) * 4);
    }
#pragma unroll
    for (int k = 0; k < 4; k++) {
        int ls = l - 3 + k;
        if (ls >= 0) {
            f16x8 xv = *(const f16x8*)(xz + (size_t)(m + k - 3) * 4096 + d0);
#pragma unroll
            for (int j = 0; j < 8; j++) r[j] += cwv[j][k] * (float)xv[j];
        }
    }
    f16x8 o;
#pragma unroll
    for (int j = 0; j < 8; j++) o[j] = (f16)silu_f(r[j]);
    *(f16x8*)(xc + (size_t)m * 2048 + d0) = o;
}

// ---------------- chunked selective scan, 2 states per lane ----------------
// L=2048 -> NCHUNK=32 chunks of CT=64. 8 lanes per (b,d) chain; lane owns states n, n+8.
// 32 chains per block (256 thr). grid = (chunk, dgroup=64, b=2).
#define CT 64
#define NCHUNK 32
#define NSTATE 65536  // 2*2048*16

// Pass 1: local scan from h=0 -> Hend; chunk decay P = exp(A * sum dt)
__global__ __launch_bounds__(256) void scan_p1(const f16* __restrict__ dt16, const f16* __restrict__ xc,
                                               const float* __restrict__ proj, const float* __restrict__ A_log,
                                               float* __restrict__ Pbuf, float* __restrict__ Hend) {
    __shared__ f32x2 du_s[CT][32];  // {dt, dt*x} 16KB
    __shared__ f32x2 b_s[CT][8];    // {B[n], B[n+8]} 4KB
    const int tid = threadIdx.x;
    const int c = blockIdx.x, dg = blockIdx.y, b = blockIdx.z;
    const int d_base = dg << 5;
    const int g = tid >> 3, n = tid & 7;
    const int d = d_base + g;
    const float a0 = -fast_exp(A_log[d * 16 + n]) * LOG2E;
    const float a1 = -fast_exp(A_log[d * 16 + n + 8]) * LOG2E;
    const size_t mb = (size_t)b * 2048 + c * CT;

#pragma unroll
    for (int i = 0; i < 8; i++) {
        int idx = i * 256 + tid, tt = idx >> 5, j = idx & 31;
        size_t row = mb + tt;
        float dtv = (float)dt16[row * 2048 + d_base + j];
        float xv = (float)xc[row * 2048 + d_base + j];
        du_s[tt][j] = (f32x2){dtv, dtv * xv};
    }
#pragma unroll
    for (int i = 0; i < 2; i++) {
        int idx = i * 256 + tid, tt = idx >> 3, jn = idx & 7;
        size_t row = mb + tt;
        b_s[tt][jn] = (f32x2){proj[row * 128 + 64 + jn], proj[row * 128 + 72 + jn]};
    }
    __syncthreads();

    float h0 = 0.f, h1 = 0.f, sdt = 0.f;
#pragma unroll 8
    for (int t = 0; t < CT; t++) {
        f32x2 du = du_s[t][g];
        f32x2 bv = b_s[t][n];
        float e0 = __builtin_amdgcn_exp2f(du[0] * a0);
        float e1 = __builtin_amdgcn_exp2f(du[0] * a1);
        sdt += du[0];
        h0 = fmaf(e0, h0, du[1] * bv[0]);
        h1 = fmaf(e1, h1, du[1] * bv[1]);
    }
    const size_t sidx = (size_t)c * NSTATE + ((b << 11) + d) * 16 + n;
    Pbuf[sidx] = __builtin_amdgcn_exp2f(a0 * sdt);
    Pbuf[sidx + 8] = __builtin_amdgcn_exp2f(a1 * sdt);
    Hend[sidx] = h0;
    Hend[sidx + 8] = h1;
}

// Combine: sequential prefix over chunks (parallel over 65536 states)
__global__ __launch_bounds__(256) void scan_combine(const float* __restrict__ Pbuf, const float* __restrict__ Hend,
                                                    float* __restrict__ Hinit) {
    int s = blockIdx.x * 256 + threadIdx.x;
    float h = 0.f;
#pragma unroll
    for (int c = 0; c < NCHUNK; c++) {
        Hinit[(size_t)c * NSTATE + s] = h;
        h = fmaf(Pbuf[(size_t)c * NSTATE + s], h, Hend[(size_t)c * NSTATE + s]);
    }
}

// Pass 2: scan seeded with Hinit; fused y = (C.h)*sz + D*x*sz, sz = silu(z)
__global__ __launch_bounds__(256) void scan_p2(const f16* __restrict__ dt16, const f16* __restrict__ xc,
                                               const f16* __restrict__ xz, const float* __restrict__ proj,
                                               const float* __restrict__ A_log, const float* __restrict__ Dp,
                                               const float* __restrict__ Hinit, f16* __restrict__ y16) {
    __shared__ f32x2 du_s[CT][32];  // {dt, dt*x}                    16KB
    __shared__ f32x4 bc_s[CT][8];   // {B[n],B[n+8],C[n],C[n+8]}      8KB
    __shared__ float gz_s[CT][32];  // pack f16x2 {silu(z), D*x*silu(z)} 8KB
    const int tid = threadIdx.x;
    const int c = blockIdx.x, dg = blockIdx.y, b = blockIdx.z;
    const int d_base = dg << 5;
    const int g = tid >> 3, n = tid & 7;
    const int d = d_base + g;
    const float a0 = -fast_exp(A_log[d * 16 + n]) * LOG2E;
    const float a1 = -fast_exp(A_log[d * 16 + n + 8]) * LOG2E;
    const size_t mb = (size_t)b * 2048 + c * CT;

#pragma unroll
    for (int i = 0; i < 8; i++) {
        int idx = i * 256 + tid, tt = idx >> 5, j = idx & 31;
        size_t row = mb + tt;
        float dtv = (float)dt16[row * 2048 + d_base + j];
        float xv = (float)xc[row * 2048 + d_base + j];
        float zv = (float)xz[row * 4096 + 2048 + d_base + j];
        float sz = silu_f(zv);
        du_s[tt][j] = (f32x2){dtv, dtv * xv};
        union { f16x2 h2; float f; } u;
        u.h2[0] = (f16)sz;
        u.h2[1] = (f16)(Dp[d_base + j] * xv * sz);
        gz_s[tt][j] = u.f;
    }
#pragma unroll
    for (int i = 0; i < 2; i++) {
        int idx = i * 256 + tid, tt = idx >> 3, jn = idx & 7;
        size_t row = mb + tt;
        bc_s[tt][jn] = (f32x4){proj[row * 128 + 64 + jn], proj[row * 128 + 72 + jn],
                               proj[row * 128 + 80 + jn], proj[row * 128 + 88 + jn]};
    }
    const size_t sidx = (size_t)c * NSTATE + ((b << 11) + d) * 16 + n;
    float h0 = Hinit[sidx];
    float h1 = Hinit[sidx + 8];
    __syncthreads();

#pragma unroll 8
    for (int t = 0; t < CT; t++) {
        f32x2 du = du_s[t][g];
        f32x4 bc = bc_s[t][n];
        float e0 = __builtin_amdgcn_exp2f(du[0] * a0);
        float e1 = __builtin_amdgcn_exp2f(du[0] * a1);
        h0 = fmaf(e0, h0, du[1] * bc[0]);
        h1 = fmaf(e1, h1, du[1] * bc[1]);
        float yp = fmaf(h1, bc[3], h0 * bc[2]);
        yp = DPP_ADD(yp, 0xB1);   // xor 1
        yp = DPP_ADD(yp, 0x4E);   // xor 2
        yp = DPP_ADD(yp, 0x141);  // xor 4 (within 8-lane group)
        union { float f; f16x2 h2; } u;
        u.f = gz_s[t][g];
        float yv = fmaf(yp, (float)u.h2[0], (float)u.h2[1]);
        if (n == 0) y16[(mb + t) * 2048 + d] = (f16)yv;
    }
}

extern "C" void kernel_launch(void* const* d_in, const int* in_sizes, int n_in,
                              void* d_out, int out_size, void* d_ws, size_t ws_size,
                              hipStream_t stream) {
    const float* hidden = (const float*)d_in[0];
    const float* W_in   = (const float*)d_in[1];
    const float* conv_w = (const float*)d_in[2];
    const float* conv_b = (const float*)d_in[3];
    const float* W_x    = (const float*)d_in[4];
    const float* W_dt   = (const float*)d_in[5];
    const float* b_dt   = (const float*)d_in[6];
    const float* A_log  = (const float*)d_in[7];
    const float* D_par  = (const float*)d_in[8];
    const float* W_out  = (const float*)d_in[9];
    float* out = (float*)d_out;

    char* ws = (char*)d_ws;
    size_t off = 0;
    auto alloc = [&](size_t bytes) { void* p = ws + off; off += (bytes + 255) & ~(size_t)255; return p; };
    f16* h16     = (f16*)alloc(4096ull * 1024 * 2);
    f16* Win16   = (f16*)alloc(4096ull * 1024 * 2);
    f16* Wx16    = (f16*)alloc(128ull * 2048 * 2);
    f16* Wdt16   = (f16*)alloc(2048ull * 64 * 2);
    f16* Wout16  = (f16*)alloc(1024ull * 2048 * 2);
    f16* xz16    = (f16*)alloc(4096ull * 4096 * 2);
    f16* xc16    = (f16*)alloc(4096ull * 2048 * 2);
    float* proj  = (float*)alloc(4096ull * 128 * 4);
    f16* dtlo16  = (f16*)alloc(4096ull * 64 * 2);
    f16* dt16    = (f16*)alloc(4096ull * 2048 * 2);
    f16* y16     = (f16*)alloc(4096ull * 2048 * 2);
    float* Pws   = (float*)y16;  // alias: split-K partials (16MB) dead before scan_p2 writes y16
    float* Pbuf  = (float*)alloc((size_t)NCHUNK * NSTATE * 4);
    float* Hend  = (float*)alloc((size_t)NCHUNK * NSTATE * 4);
    float* Hinit = (float*)alloc((size_t)NCHUNK * NSTATE * 4);
    (void)ws_size; (void)in_sizes; (void)n_in; (void)out_size;

    // fp32 -> fp16 operand prep
    cvt_f32_f16<<<4096, 256, 0, stream>>>(hidden, h16, 1048576);
    cvt_f32_f16<<<4096, 256, 0, stream>>>(W_in, Win16, 1048576);
    cvt_wx<<<1024, 256, 0, stream>>>(W_x, Wx16);
    cvt_f32_f16<<<128, 256, 0, stream>>>(W_dt, Wdt16, 32768);
    cvt_f32_f16<<<2048, 256, 0, stream>>>(W_out, Wout16, 524288);

    // in_proj: xz = hidden @ W_in^T   (4096 x 4096 x 1024)
    gemm_gl<0, f16><<<dim3(32, 32, 1), 256, 0, stream>>>(h16, Win16, xz16, nullptr, 4096, 4096, 1024, 1024);
    // depthwise conv + SiLU
    conv_silu_k<<<4096, 256, 0, stream>>>(xz16, conv_w, conv_b, xc16);
    // x_proj with split-K=8: Pws[z] = xc @ Wx^T over K-slice z
    gemm_gl<0, float><<<dim3(1, 32, 8), 256, 0, stream>>>(xc16, Wx16, Pws, nullptr, 4096, 128, 2048, 256);
    reduce_proj<<<512, 256, 0, stream>>>(Pws, proj, dtlo16);
    // dt = softplus(dtlo @ W_dt^T + b_dt) -> f16
    gemm_gl<1, f16><<<dim3(16, 32, 1), 256, 0, stream>>>(dtlo16, Wdt16, dt16, b_dt, 4096, 2048, 64, 64);
    // chunked selective scan + gating -> y16
    scan_p1<<<dim3(NCHUNK, 64, 2), 256, 0, stream>>>(dt16, xc16, proj, A_log, Pbuf, Hend);
    scan_combine<<<256, 256, 0, stream>>>(Pbuf, Hend, Hinit);
    scan_p2<<<dim3(NCHUNK, 64, 2), 256, 0, stream>>>(dt16, xc16, xz16, proj, A_log, D_par, Hinit, y16);
    // out_proj: out = y @ W_out^T
    gemm_gl<0, float><<<dim3(8, 32, 1), 256, 0, stream>>>(y16, Wout16, out, nullptr, 4096, 1024, 2048, 2048);
}